// Round 16
// baseline (502.143 us; speedup 1.0000x reference)
//
#include <hip/hip_runtime.h>

#define NN 50000
#define EE 40000
#define PP 4096
#define MAXR 12
#define SCAP 16
#define NB 8192
#define TANCH 2
#define TSTEPS 10
#define TGRID 512

typedef unsigned short us;
typedef __attribute__((ext_vector_type(8))) short bf8v;
typedef __attribute__((ext_vector_type(4))) float f4v;

__device__ __forceinline__ us f2b(float x) {
    unsigned u = __float_as_uint(x);
    u = (u + 0x7fffu + ((u >> 16) & 1u)) >> 16;
    return (us)u;
}
__device__ __forceinline__ float b2f(us h) {
    return __uint_as_float(((unsigned)h) << 16);
}
__device__ __forceinline__ unsigned fkey(float f) {
    unsigned u = __float_as_uint(f);
    return (u & 0x80000000u) ? ~u : (u | 0x80000000u);
}
__device__ __forceinline__ float funkey(unsigned k) {
    unsigned u = (k & 0x80000000u) ? (k & 0x7fffffffu) : ~k;
    return __uint_as_float(u);
}
__device__ __forceinline__ int bucket_of(float tv) {
    int b = (int)(tv * 8192.0f);
    if (b < 0) b = 0;
    if (b > NB - 1) b = NB - 1;
    return b;
}
__device__ __forceinline__ unsigned relu2bf(unsigned u) {
    unsigned lo = (u & 0x8000u) ? 0u : (u & 0xFFFFu);
    unsigned hi = (u & 0x80000000u) ? 0u : (u & 0xFFFF0000u);
    return lo | hi;
}

// ---------------- needed nodes / edges / U-set ----------------

__global__ void k_elist(const int* __restrict__ src, const int* __restrict__ dst,
                        const int* __restrict__ needed, int* __restrict__ necnt,
                        int* __restrict__ eidx, int* __restrict__ uneed)
{
    __shared__ int lc, lb;
    if (threadIdx.x == 0) lc = 0;
    __syncthreads();
    int e = blockIdx.x * 256 + threadIdx.x;
    int slot = -1;
    if (e < EE && needed[dst[e]]) {
        slot = atomicAdd(&lc, 1);
        uneed[dst[e]] = 1;
        uneed[src[e]] = 1;
    }
    __syncthreads();
    if (threadIdx.x == 0 && lc) lb = atomicAdd(necnt, lc);
    __syncthreads();
    if (slot >= 0) eidx[lb + slot] = e;
}

__global__ void k_ulist(const int* __restrict__ uneed, int* __restrict__ ucnt,
                        int* __restrict__ ulist, int* __restrict__ nidx)
{
    __shared__ int lc, lb;
    if (threadIdx.x == 0) lc = 0;
    __syncthreads();
    int n = blockIdx.x * 256 + threadIdx.x;
    int slot = -1;
    if (n < NN && uneed[n]) slot = atomicAdd(&lc, 1);
    __syncthreads();
    if (threadIdx.x == 0 && lc) lb = atomicAdd(ucnt, lc);
    __syncthreads();
    if (slot >= 0) { ulist[lb + slot] = n; nidx[n] = lb + slot; }
}

// ---------------- ordering (k_need fused in as first 16 blocks) ----------------

__global__ __launch_bounds__(256) void k_prep(const int* __restrict__ pm, int* __restrict__ needed,
                                              const float* __restrict__ t, const int* __restrict__ src,
                                              int* __restrict__ hist, int* __restrict__ scnt,
                                              int* __restrict__ slist, unsigned* __restrict__ tm)
{
    if (blockIdx.x < 16) {
        int i = blockIdx.x * 256 + threadIdx.x;
        if (i < PP) needed[pm[i]] = 1;
        return;
    }
    int e = (blockIdx.x - 16) * 256 + threadIdx.x;
    float v = 0.f;
    if (e < EE) {
        float tv = t[e];
        v = tv;
        atomicAdd(&hist[bucket_of(tv)], 1);
        int s = src[e];
        int slot = atomicAdd(&scnt[s], 1);
        if (slot < SCAP) slist[s * SCAP + slot] = e;
    }
#pragma unroll
    for (int o = 32; o > 0; o >>= 1) v = fmaxf(v, __shfl_xor(v, o));
    if ((threadIdx.x & 63) == 0) atomicMax(tm, fkey(v));
}

// single-block exclusive prefix scan over NB=8192 bins
__global__ __launch_bounds__(256) void k_scanone(const int* __restrict__ hist, int* __restrict__ hbase)
{
    __shared__ int tot[256];
    int t = threadIdx.x;
    int base = t * (NB / 256);
    int loc[NB / 256];
    int s = 0;
#pragma unroll
    for (int i = 0; i < NB / 256; ++i) { loc[i] = s; s += hist[base + i]; }
    tot[t] = s;
    __syncthreads();
    for (int o = 1; o < 256; o <<= 1) {
        int x = (t >= o) ? tot[t - o] : 0;
        __syncthreads();
        tot[t] += x;
        __syncthreads();
    }
    int off = tot[t] - s;   // exclusive
#pragma unroll
    for (int i = 0; i < NB / 256; ++i) hbase[base + i] = loc[i] + off;
}

__global__ void k_bscatter(const float* __restrict__ t, const int* __restrict__ hbase,
                           int* __restrict__ hcur, int* __restrict__ blist)
{
    int e = blockIdx.x * 256 + threadIdx.x;
    if (e >= EE) return;
    int b = bucket_of(t[e]);
    int p = hbase[b] + atomicAdd(&hcur[b], 1);
    blist[p] = e;
}

__global__ void k_rank2(const float* __restrict__ t, const int* __restrict__ hbase,
                        const int* __restrict__ hist, const int* __restrict__ blist,
                        int* __restrict__ rank)
{
    int e = blockIdx.x * 256 + threadIdx.x;
    if (e >= EE) return;
    float te_ = t[e];
    int b = bucket_of(te_);
    int base = hbase[b], cnt = hist[b];
    int r = base;
    for (int i = 0; i < cnt; ++i) {
        int j = blist[base + i];
        float tj = t[j];
        r += (tj < te_ || (tj == te_ && j < e)) ? 1 : 0;
    }
    rank[e] = r;
}

// chain decomposition (filtered) + round insert + xpart compaction
__global__ void k_chain(const int* __restrict__ src, const int* __restrict__ rank,
                        const int* __restrict__ scnt, const int* __restrict__ slist,
                        const int* __restrict__ uneed,
                        int* __restrict__ roundcnt, int* __restrict__ roundx, int* __restrict__ roundsrc,
                        int* __restrict__ xcnt, int* __restrict__ xlist, int* __restrict__ xsrc)
{
    __shared__ int lcnt[MAXR];
    __shared__ int lbase[MAXR];
    __shared__ int xl, xb;
    int tid = threadIdx.x;
    if (tid < MAXR) lcnt[tid] = 0;
    if (tid == 0) xl = 0;
    __syncthreads();
    int e = blockIdx.x * 256 + tid;
    int pos = -1, slot = 0, xs = 0, ssave = 0;
    if (e < EE && uneed[src[e]]) {
        int s = src[e];
        int c = scnt[s]; if (c > SCAP) c = SCAP;
        int re = rank[e], be = re / 200;
        bool r_e = true;
        for (int i = 0; i < c; ++i) {
            int rj = rank[slist[s * SCAP + i]];
            if (rj / 200 == be && rj > re) { r_e = false; break; }
        }
        if (r_e) {
            int p = 0;
            for (int i = 0; i < c; ++i) {
                int rj = rank[slist[s * SCAP + i]];
                if (rj >= re) continue;
                int bj = rj / 200;
                bool r_j = true;
                for (int k2 = 0; k2 < c; ++k2) {
                    int rj2 = rank[slist[s * SCAP + k2]];
                    if (rj2 / 200 == bj && rj2 > rj) { r_j = false; break; }
                }
                p += r_j ? 1 : 0;
            }
            if (p < MAXR) { pos = p; ssave = s; slot = atomicAdd(&lcnt[p], 1); xs = atomicAdd(&xl, 1); }
        }
    }
    __syncthreads();
    if (tid < MAXR && lcnt[tid]) lbase[tid] = atomicAdd(&roundcnt[tid], lcnt[tid]);
    if (tid == 0 && xl) xb = atomicAdd(xcnt, xl);
    __syncthreads();
    if (pos >= 0) {
        int xr = xb + xs;
        xlist[xr] = e;
        xsrc[xr] = ssave;
        size_t o = (size_t)pos * EE + lbase[pos] + slot;
        roundx[o] = xr;
        roundsrc[o] = ssave;
    }
}

// ---------------- targeted zero / conversions ----------------

// fused: zero memb/memb_bf + convert nf rows at U nodes
__global__ void k_zcvt(const int* __restrict__ ucnt, const int* __restrict__ ulist,
                       const float* __restrict__ nf, us* __restrict__ nf_bf,
                       float* __restrict__ memb, us* __restrict__ memb_bf)
{
    int total = *ucnt * 64;
    for (int i = blockIdx.x * 256 + threadIdx.x; i < total; i += gridDim.x * 256) {
        int n = ulist[i >> 6], q = i & 63;
        reinterpret_cast<float4*>(memb + (size_t)n * 256)[q] = make_float4(0.f, 0.f, 0.f, 0.f);
        reinterpret_cast<ushort4*>(memb_bf + (size_t)n * 256)[q] = make_ushort4(0, 0, 0, 0);
        float4 v = reinterpret_cast<const float4*>(nf + (size_t)n * 256)[q];
        ushort4 o; o.x = f2b(v.x); o.y = f2b(v.y); o.z = f2b(v.z); o.w = f2b(v.w);
        reinterpret_cast<ushort4*>(nf_bf + (size_t)n * 256)[q] = o;
    }
}

// te (sin) + ea conversion over BOTH edge lists in one launch
__global__ void k_convL2(const int* __restrict__ xcnt, const int* __restrict__ xlist,
                         const int* __restrict__ necnt, const int* __restrict__ eidx,
                         const float* __restrict__ t, const float* __restrict__ w,
                         const float* __restrict__ b, us* __restrict__ te,
                         const float* __restrict__ ea, us* __restrict__ ea_bf)
{
    int t1 = *xcnt * 32, t2 = *necnt * 32;
    int total = t1 + t2;
    for (int i = blockIdx.x * 256 + threadIdx.x; i < total; i += gridDim.x * 256) {
        int ii = i;
        const int* lst = xlist;
        if (ii >= t1) { ii -= t1; lst = eidx; }
        int e = lst[ii >> 5], q = (ii & 31) * 4;
        float tv = t[e];
        ushort4 ot;
        ot.x = f2b(sinf(tv * w[q] + b[q]));
        ot.y = f2b(sinf(tv * w[q + 1] + b[q + 1]));
        ot.z = f2b(sinf(tv * w[q + 2] + b[q + 2]));
        ot.w = f2b(sinf(tv * w[q + 3] + b[q + 3]));
        *reinterpret_cast<ushort4*>(te + (size_t)e * 128 + q) = ot;
        float4 v = *reinterpret_cast<const float4*>(ea + (size_t)e * 128 + q);
        ushort4 oa; oa.x = f2b(v.x); oa.y = f2b(v.y); oa.z = f2b(v.z); oa.w = f2b(v.w);
        *reinterpret_cast<ushort4*>(ea_bf + (size_t)e * 128 + q) = oa;
    }
}

__global__ void k_zout(const int* __restrict__ pm, float* __restrict__ outb,
                       float* __restrict__ denom, unsigned* __restrict__ mx)
{
    int i = blockIdx.x * 256 + threadIdx.x;
    int p = i >> 6, q = i & 63;
    if (p >= PP) return;
    int n = pm[p];
    reinterpret_cast<float4*>(outb + (size_t)n * 256)[q] = make_float4(0.f, 0.f, 0.f, 0.f);
    if (q == 0) { denom[n] = 0.f; mx[n] = 0u; }
}

// k-major bf16 weight copies + interleaved (Wi,Wh) pair buffer for the tail walker
__global__ void k_wkflat(const float* __restrict__ sa, us* __restrict__ da, int na4,
                         const float* __restrict__ sb, us* __restrict__ db, int nb4,
                         const float* __restrict__ Wi, const float* __restrict__ Wh,
                         us* __restrict__ Wk_ih, int nih)
{
    int i = blockIdx.x * 256 + threadIdx.x;
    int j = i;
    if (j < na4) {
        float4 v = reinterpret_cast<const float4*>(sa)[j];
        ushort4 o; o.x = f2b(v.x); o.y = f2b(v.y); o.z = f2b(v.z); o.w = f2b(v.w);
        reinterpret_cast<ushort4*>(da)[j] = o;
        return;
    }
    j -= na4;
    if (j < nb4) {
        float4 v = reinterpret_cast<const float4*>(sb)[j];
        ushort4 o; o.x = f2b(v.x); o.y = f2b(v.y); o.z = f2b(v.z); o.w = f2b(v.w);
        reinterpret_cast<ushort4*>(db)[j] = o;
        return;
    }
    j -= nb4;
    if (j < nih) {
        unsigned lo = (unsigned)f2b(Wi[j]);
        unsigned hi = (unsigned)f2b(Wh[j]);
        reinterpret_cast<unsigned*>(Wk_ih)[j] = lo | (hi << 16);
    }
}

// ---------------- tiled weight transpose (+ gvec block) ----------------

struct WtD { const float* W; us* dst; int K, N, ld, koff, Ktot, toff; };
struct WtA { WtD d[12]; int ntiles; };

__global__ __launch_bounds__(256) void k_wt2(WtA wa, const unsigned* __restrict__ tm,
                                             const float* __restrict__ wt, const float* __restrict__ bt,
                                             const float* __restrict__ Wg, float* __restrict__ gvec)
{
    if ((int)blockIdx.x == wa.ntiles) {
        __shared__ float sv[128];
        int c = threadIdx.x;
        float tmax = funkey(*tm);
        if (c < 128) sv[c] = sinf(tmax * wt[c] + bt[c]);
        __syncthreads();
        float acc = 0.f;
        for (int k = 0; k < 128; ++k) acc += sv[k] * Wg[(size_t)(512 + k) * 256 + c];
        gvec[c] = acc;
        return;
    }
    int bid = blockIdx.x;
    int di = 0;
#pragma unroll
    for (int i = 1; i < 12; ++i) if (bid >= wa.d[i].toff) di = i;
    WtD d = wa.d[di];
    int tt = bid - d.toff;
    int tn = d.N >> 5;
    int k0 = (tt / tn) << 5, n0 = (tt % tn) << 5;
    __shared__ float ld[32][33];
    int tx = threadIdx.x & 31, ty = threadIdx.x >> 5;
#pragma unroll
    for (int i = 0; i < 4; ++i)
        ld[ty + 8 * i][tx] = d.W[(size_t)(k0 + ty + 8 * i) * d.ld + n0 + tx];
    __syncthreads();
#pragma unroll
    for (int i = 0; i < 4; ++i) {
        int n = n0 + ty + 8 * i;
        d.dst[(size_t)n * d.Ktot + d.koff + k0 + tx] = f2b(ld[tx][ty + 8 * i]);
    }
}

// ---------------- MFMA GEMM ----------------
__global__ __launch_bounds__(256) void k_mgemm(
    const us* __restrict__ A1, int K1, const int* __restrict__ idx1,
    const us* __restrict__ A2, int K2, const int* __restrict__ idx2,
    const us* __restrict__ A3, int K3, const int* __restrict__ idx3,
    const us* __restrict__ Wt, int Kloop, int ldw,
    const float* __restrict__ bias,
    const us* __restrict__ Cin, const int* __restrict__ cidx,
    float* __restrict__ outF, us* __restrict__ outB, int ldc,
    int Mhost, const int* __restrict__ mdev, int mbase, int relu, int relua)
{
    int M = Mhost;
    if (mdev) {
        int avail = *mdev - mbase;
        if (avail < 0) avail = 0;
        if (avail < M) M = avail;
    }
    const int row0 = blockIdx.x * 128;
    if (row0 >= M) return;
    const int col0 = blockIdx.y * 64;

    __shared__ us As[128 * 64];
    __shared__ us Bs[64 * 64];

    const int tid = threadIdx.x;
    const int l = tid & 63;
    const int wv = tid >> 6;

    f4v acc[2][4];
#pragma unroll
    for (int i = 0; i < 2; ++i)
#pragma unroll
        for (int j = 0; j < 4; ++j) acc[i][j] = (f4v){0.f, 0.f, 0.f, 0.f};

    for (int k0 = 0; k0 < Kloop; k0 += 64) {
#pragma unroll
        for (int it = 0; it < 4; ++it) {
            int idx = tid + it * 256;
            int r = idx >> 3, q = idx & 7;
            int gk = k0 + q * 8;
            int grow = row0 + r;
            uint4 v = make_uint4(0u, 0u, 0u, 0u);
            if (grow < M) {
                const us* sp; int st, krel, ar = grow;
                if (gk < K1) {
                    sp = A1; st = K1; krel = gk;
                    if (idx1) ar = idx1[ar];
                } else if (gk < K1 + K2) {
                    sp = A2; st = K2; krel = gk - K1;
                    if (idx2) ar = idx2[ar];
                } else {
                    sp = A3; st = K3; krel = gk - K1 - K2;
                    if (idx3) ar = idx3[ar];
                }
                v = *reinterpret_cast<const uint4*>(sp + (size_t)ar * st + krel);
                if (relua) { v.x = relu2bf(v.x); v.y = relu2bf(v.y); v.z = relu2bf(v.z); v.w = relu2bf(v.w); }
            }
            *reinterpret_cast<uint4*>(As + r * 64 + ((q ^ (r & 7)) << 3)) = v;
        }
#pragma unroll
        for (int it = 0; it < 2; ++it) {
            int idx = tid + it * 256;
            int c = idx >> 3, q = idx & 7;
            uint4 v = *reinterpret_cast<const uint4*>(Wt + (size_t)(col0 + c) * ldw + k0 + q * 8);
            *reinterpret_cast<uint4*>(Bs + c * 64 + ((q ^ (c & 7)) << 3)) = v;
        }
        __syncthreads();
#pragma unroll
        for (int ks = 0; ks < 2; ++ks) {
            bf8v af[2], bfr[4];
#pragma unroll
            for (int mf = 0; mf < 2; ++mf) {
                int r = wv * 32 + mf * 16 + (l & 15);
                int q = ks * 4 + (l >> 4);
                af[mf] = *reinterpret_cast<const bf8v*>(As + r * 64 + ((q ^ (r & 7)) << 3));
            }
#pragma unroll
            for (int nf = 0; nf < 4; ++nf) {
                int c = nf * 16 + (l & 15);
                int q = ks * 4 + (l >> 4);
                bfr[nf] = *reinterpret_cast<const bf8v*>(Bs + c * 64 + ((q ^ (c & 7)) << 3));
            }
#pragma unroll
            for (int mf = 0; mf < 2; ++mf)
#pragma unroll
                for (int nf = 0; nf < 4; ++nf)
                    acc[mf][nf] = __builtin_amdgcn_mfma_f32_16x16x32_bf16(af[mf], bfr[nf], acc[mf][nf], 0, 0, 0);
        }
        __syncthreads();
    }

#pragma unroll
    for (int mf = 0; mf < 2; ++mf) {
#pragma unroll
        for (int rr = 0; rr < 4; ++rr) {
            int row = row0 + wv * 32 + mf * 16 + ((l >> 4) * 4) + rr;
            if (row >= M) continue;
            size_t crow = 0;
            if (Cin) crow = (size_t)(cidx ? cidx[row] : row) * ldc;
#pragma unroll
            for (int nf = 0; nf < 4; ++nf) {
                int col = col0 + nf * 16 + (l & 15);
                float v = acc[mf][nf][rr];
                if (bias) v += bias[col];
                if (Cin) v += b2f(Cin[crow + col]);
                if (relu) v = fmaxf(v, 0.f);
                if (outF) outF[(size_t)row * ldc + col] = v;
                if (outB) outB[(size_t)row * ldc + col] = f2b(v);
            }
        }
    }
}

// ---------------- scan helpers ----------------

__global__ void k_hgather(const int* __restrict__ cnt, int cb, int m, const int* __restrict__ rs,
                          const us* __restrict__ mem_bf, us* __restrict__ hprev)
{
    int idx = blockIdx.x * 256 + threadIdx.x;
    int i = idx >> 6, q = idx & 63;
    int avail = *cnt - cb;
    if (avail > m) avail = m;
    if (i >= avail) return;
    int s = rs[i];
    reinterpret_cast<ushort4*>(hprev + (size_t)i * 256)[q] =
        reinterpret_cast<const ushort4*>(mem_bf + (size_t)s * 256)[q];
}

// grid-stride over rows (fixed grid)
__global__ void k_gate(const int* __restrict__ cnt, int cb, int m, const int* __restrict__ rs,
                       const us* __restrict__ gates, const float* __restrict__ bi,
                       const float* __restrict__ bh,
                       float* __restrict__ mem, us* __restrict__ mem_bf)
{
    int avail = *cnt - cb;
    if (avail > m) avail = m;
    int c = threadIdx.x;
    for (int i = blockIdx.x; i < avail; i += gridDim.x) {
        int s = rs[i];
        float hp = mem[(size_t)s * 256 + c];
        const us* g = gates + (size_t)i * 1024;
        float g0 = b2f(g[c]) + bi[c] + bh[c];
        float g1 = b2f(g[256 + c]) + bi[256 + c] + bh[256 + c];
        float g2i = b2f(g[512 + c]) + bi[512 + c];
        float g2h = b2f(g[768 + c]) + bh[512 + c];
        float r = 1.f / (1.f + expf(-g0));
        float z = 1.f / (1.f + expf(-g1));
        float n = tanhf(g2i + r * g2h);
        float hnew = (1.f - z) * n + z * hp;
        mem[(size_t)s * 256 + c] = hnew;
        mem_bf[(size_t)s * 256 + c] = f2b(hnew);
    }
}

// build per-source tail chains anchored at round TANCH
__global__ void k_tbuild(const int* __restrict__ roundcnt, const int* __restrict__ roundx,
                         const int* __restrict__ roundsrc, int* __restrict__ tx)
{
    int i = blockIdx.x * 256 + threadIdx.x;
    if (i >= roundcnt[TANCH]) return;
    int s = roundsrc[(size_t)TANCH * EE + i];
    tx[i * TSTEPS + 0] = roundx[(size_t)TANCH * EE + i];
#pragma unroll
    for (int k = 1; k < TSTEPS; ++k) tx[i * TSTEPS + k] = -1;
    for (int j = TANCH + 1; j < MAXR; ++j) {
        int cj = roundcnt[j];
        for (int m2 = 0; m2 < cj; ++m2) {
            if (roundsrc[(size_t)j * EE + m2] == s) {
                tx[i * TSTEPS + (j - TANCH)] = roundx[(size_t)j * EE + m2];
                break;
            }
        }
    }
}

// fixed-grid chain walker. Round-15 lesson: phase3 was L2-latency bound with
// only 16 loads in flight per thread; k-pair processing (2 loads + 4 FMAs per
// iter, 4 independent accumulators, unroll 16 -> 32 outstanding loads) halves
// the latency rounds without the register-spill blowup of rounds 9-11.
__global__ __launch_bounds__(1024) void k_tailchain(
    const int* __restrict__ roundcnt, const int* __restrict__ roundsrc, const int* __restrict__ tx,
    const us* __restrict__ xpart_c, const us* __restrict__ Wk_a, const us* __restrict__ Wk_m2,
    const us* __restrict__ Wk_ih, const float* __restrict__ bm2,
    const float* __restrict__ bi, const float* __restrict__ bh,
    float* __restrict__ mem, us* __restrict__ mem_bf)
{
    const int cnt = roundcnt[TANCH];
    const int tid = threadIdx.x;
    const int c = tid & 255;
    const int p = tid >> 8;          // 0..3 (init/gate lanes use p==0)
    const int c2 = (tid & 127) * 2;  // channel pair for phases 1/2
    const int kp = tid >> 7;         // 0..7 k-eighth
    __shared__ float hb[256];
    __shared__ float xv[256];
    __shared__ float msgv[256];
    __shared__ float red[8][256];
    __shared__ float oi[768];
    __shared__ float oh[768];
    for (int i = blockIdx.x; i < cnt; i += gridDim.x) {
        int s = roundsrc[(size_t)TANCH * EE + i];
        float hp = 0.f;
        if (p == 0) { hp = mem[(size_t)s * 256 + c]; hb[c] = hp; }
        __syncthreads();
        for (int k = 0; k < TSTEPS; ++k) {
            int xr = tx[i * TSTEPS + k];
            if (xr < 0) break;
            // phase1: xv = relu(xpart + hb@Wm1a)
            {
                float a0 = 0.f, a1 = 0.f;
                int k0 = kp * 32;
#pragma unroll 16
                for (int kk = 0; kk < 32; ++kk) {
                    unsigned w = *reinterpret_cast<const unsigned*>(Wk_a + (size_t)(k0 + kk) * 256 + c2);
                    float hv = hb[k0 + kk];
                    a0 += b2f((us)(w & 0xffffu)) * hv;
                    a1 += b2f((us)(w >> 16)) * hv;
                }
                red[kp][c2] = a0;
                red[kp][c2 + 1] = a1;
            }
            __syncthreads();
            if (p == 0) {
                float a = b2f(xpart_c[(size_t)xr * 256 + c]);
#pragma unroll
                for (int r8 = 0; r8 < 8; ++r8) a += red[r8][c];
                xv[c] = fmaxf(a, 0.f);
            }
            __syncthreads();
            // phase2: msg = relu(xv@Wm2 + bm2)
            {
                float a0 = 0.f, a1 = 0.f;
                int k0 = kp * 32;
#pragma unroll 16
                for (int kk = 0; kk < 32; ++kk) {
                    unsigned w = *reinterpret_cast<const unsigned*>(Wk_m2 + (size_t)(k0 + kk) * 256 + c2);
                    float hv = xv[k0 + kk];
                    a0 += b2f((us)(w & 0xffffu)) * hv;
                    a1 += b2f((us)(w >> 16)) * hv;
                }
                red[kp][c2] = a0;
                red[kp][c2 + 1] = a1;
            }
            __syncthreads();
            if (p == 0) {
                float a = bm2[c];
#pragma unroll
                for (int r8 = 0; r8 < 8; ++r8) a += red[r8][c];
                msgv[c] = fmaxf(a, 0.f);
            }
            __syncthreads();
            // phase3: thread j<768: oi[j] = msg@Wi[:,j], oh[j] = hb@Wh[:,j].
            // k-pairs, 4 accumulators, 32 loads in flight.
            if (tid < 768) {
                float ai0 = 0.f, ah0 = 0.f, ai1 = 0.f, ah1 = 0.f;
                const unsigned* wp = reinterpret_cast<const unsigned*>(Wk_ih);
#pragma unroll 16
                for (int kk = 0; kk < 256; kk += 2) {
                    unsigned w0 = wp[(size_t)kk * 768 + tid];
                    unsigned w1 = wp[(size_t)(kk + 1) * 768 + tid];
                    ai0 += b2f((us)(w0 & 0xffffu)) * msgv[kk];
                    ah0 += b2f((us)(w0 >> 16)) * hb[kk];
                    ai1 += b2f((us)(w1 & 0xffffu)) * msgv[kk + 1];
                    ah1 += b2f((us)(w1 >> 16)) * hb[kk + 1];
                }
                oi[tid] = ai0 + ai1;
                oh[tid] = ah0 + ah1;
            }
            __syncthreads();
            if (p == 0) {
                float r = 1.f / (1.f + expf(-(oi[c] + oh[c] + bi[c] + bh[c])));
                float z = 1.f / (1.f + expf(-(oi[256 + c] + oh[256 + c] + bi[256 + c] + bh[256 + c])));
                float n = tanhf((oi[512 + c] + bi[512 + c]) + r * (oh[512 + c] + bh[512 + c]));
                hp = (1.f - z) * n + z * hp;
                hb[c] = hp;
            }
            __syncthreads();
        }
        if (p == 0) {
            mem[(size_t)s * 256 + c] = hp;
            mem_bf[(size_t)s * 256 + c] = f2b(hp);
        }
        __syncthreads();
    }
}

// ---------------- attention / head ----------------

// grid-stride over ucnt h-rows + necnt ef-rows (fixed grid; no empty-block churn)
__global__ __launch_bounds__(256) void k_dots(const us* __restrict__ hc, const us* __restrict__ efc,
                                              const int* __restrict__ ucnt, const int* __restrict__ necnt,
                                              const float* __restrict__ v_s, const float* __restrict__ v_d,
                                              const float* __restrict__ v_e,
                                              float* __restrict__ sdot, float* __restrict__ ddot,
                                              float* __restrict__ edot)
{
    int lane = threadIdx.x & 63;
    int sub = threadIdx.x >> 6;
    int u = *ucnt;
    int tot = u + *necnt;
    for (int row = blockIdx.x * 4 + sub; row < tot; row += gridDim.x * 4) {
        if (row < u) {
            ushort4 q = reinterpret_cast<const ushort4*>(hc + (size_t)row * 256)[lane];
            int c = lane * 4;
            float x0 = b2f(q.x), x1 = b2f(q.y), x2 = b2f(q.z), x3 = b2f(q.w);
            float s1 = x0 * v_s[c] + x1 * v_s[c + 1] + x2 * v_s[c + 2] + x3 * v_s[c + 3];
            float s2 = x0 * v_d[c] + x1 * v_d[c + 1] + x2 * v_d[c + 2] + x3 * v_d[c + 3];
#pragma unroll
            for (int o = 32; o > 0; o >>= 1) { s1 += __shfl_xor(s1, o); s2 += __shfl_xor(s2, o); }
            if (lane == 0) { sdot[row] = s1; ddot[row] = s2; }
        } else {
            int i = row - u;
            ushort4 q = reinterpret_cast<const ushort4*>(efc + (size_t)i * 256)[lane];
            int c = lane * 4;
            float s1 = b2f(q.x) * v_e[c] + b2f(q.y) * v_e[c + 1] + b2f(q.z) * v_e[c + 2] + b2f(q.w) * v_e[c + 3];
#pragma unroll
            for (int o = 32; o > 0; o >>= 1) s1 += __shfl_xor(s1, o);
            if (lane == 0) edot[i] = s1;
        }
    }
}

__global__ void k_logitc(const int* __restrict__ necnt, const int* __restrict__ eidx,
                         const int* __restrict__ nidx,
                         const float* __restrict__ sdot, const float* __restrict__ ddot,
                         const float* __restrict__ edot, const int* __restrict__ src,
                         const int* __restrict__ dst, float* __restrict__ logit,
                         unsigned* __restrict__ mx)
{
    int i = blockIdx.x * 256 + threadIdx.x;
    if (i >= *necnt) return;
    int e = eidx[i];
    float l = sdot[nidx[src[e]]] + ddot[nidx[dst[e]]] + edot[i];
    l = (l > 0.f) ? l : 0.2f * l;
    logit[i] = l;
    atomicMax(&mx[dst[e]], fkey(l));
}

__global__ void k_alphac(const int* __restrict__ necnt, const int* __restrict__ eidx,
                         const float* __restrict__ logit, const int* __restrict__ dst,
                         const unsigned* __restrict__ mx, float* __restrict__ alpha,
                         float* __restrict__ denom)
{
    int i = blockIdx.x * 256 + threadIdx.x;
    if (i >= *necnt) return;
    int d = dst[eidx[i]];
    float a = expf(logit[i] - funkey(mx[d]));
    alpha[i] = a;
    atomicAdd(&denom[d], a);
}

// grid-stride over needed edges (fixed grid)
__global__ void k_scatc(const int* __restrict__ necnt, const int* __restrict__ eidx,
                        const int* __restrict__ nidx,
                        const float* __restrict__ alpha, const int* __restrict__ src,
                        const int* __restrict__ dst, const us* __restrict__ hc,
                        const us* __restrict__ efc, float* __restrict__ outb)
{
    int sub = threadIdx.x >> 6;
    int c4 = threadIdx.x & 63;
    int n = *necnt;
    for (int i = blockIdx.x * 4 + sub; i < n; i += gridDim.x * 4) {
        int e = eidx[i];
        float a = alpha[i];
        ushort4 hv = reinterpret_cast<const ushort4*>(hc + (size_t)nidx[src[e]] * 256)[c4];
        ushort4 ev = reinterpret_cast<const ushort4*>(efc + (size_t)i * 256)[c4];
        float* op = outb + (size_t)dst[e] * 256 + c4 * 4;
        atomicAdd(op + 0, a * (b2f(hv.x) + b2f(ev.x)));
        atomicAdd(op + 1, a * (b2f(hv.y) + b2f(ev.y)));
        atomicAdd(op + 2, a * (b2f(hv.z) + b2f(ev.z)));
        atomicAdd(op + 3, a * (b2f(hv.w) + b2f(ev.w)));
    }
}

__global__ void k_pe(const int* __restrict__ pm, const float* __restrict__ outb,
                     const float* __restrict__ denom, us* __restrict__ pe)
{
    int p = blockIdx.x, c = threadIdx.x;
    int n = pm[p];
    pe[(size_t)p * 256 + c] = f2b(outb[(size_t)n * 256 + c] / (denom[n] + 1e-16f));
}

__global__ __launch_bounds__(256) void k_final(const float* __restrict__ c1, const float* __restrict__ Wc2,
                                               const float* __restrict__ bc2, float* __restrict__ out)
{
    int lane = threadIdx.x & 63;
    int row = blockIdx.x * 4 + (threadIdx.x >> 6);
    if (row >= PP) return;
    float s = 0.f;
    for (int c = lane; c < 128; c += 64) s += c1[(size_t)row * 128 + c] * Wc2[c];
#pragma unroll
    for (int off = 32; off > 0; off >>= 1) s += __shfl_xor(s, off);
    if (lane == 0) out[row] = 1.f / (1.f + expf(-(s + bc2[0])));
}

// ---------------- host ----------------

extern "C" void kernel_launch(void* const* d_in, const int* in_sizes, int n_in,
                              void* d_out, int out_size, void* d_ws, size_t ws_size,
                              hipStream_t stream)
{
    (void)in_sizes; (void)n_in; (void)out_size;
    const float* nf    = (const float*)d_in[0];
    const int*   ei    = (const int*)  d_in[1];
    const float* ea    = (const float*)d_in[2];
    const float* t     = (const float*)d_in[3];
    const int*   pm    = (const int*)  d_in[4];
    const float* wt    = (const float*)d_in[5];
    const float* bt    = (const float*)d_in[6];
    const float* Wm1   = (const float*)d_in[7];
    const float* bm1   = (const float*)d_in[8];
    const float* Wm2   = (const float*)d_in[9];
    const float* bm2   = (const float*)d_in[10];
    const float* Wi    = (const float*)d_in[11];
    const float* Wh    = (const float*)d_in[12];
    const float* bi    = (const float*)d_in[13];
    const float* bh    = (const float*)d_in[14];
    const float* Wg    = (const float*)d_in[15];
    const float* We    = (const float*)d_in[16];
    const float* a_src = (const float*)d_in[17];
    const float* a_dst = (const float*)d_in[18];
    const float* a_e   = (const float*)d_in[19];
    const float* Wc1   = (const float*)d_in[20];
    const float* bc1   = (const float*)d_in[21];
    const float* Wc2   = (const float*)d_in[22];
    const float* bc2   = (const float*)d_in[23];
    float* outp = (float*)d_out;
    const int* src = ei;
    const int* dst = ei + EE;

    char* base = (char*)d_ws;
    size_t off = 0;
    auto alloc = [&](size_t bytes) -> void* {
        void* p = base + off;
        off = (off + bytes + 255) & ~(size_t)255;
        return p;
    };
    int* rank      = (int*)alloc((size_t)EE * 4);
    int* roundcnt  = (int*)alloc(64 * 4);          // [0..11] rounds, [32]=tm, [33]=necnt, [34]=ucnt, [35]=xcnt
    int* roundx    = (int*)alloc((size_t)MAXR * EE * 4);
    int* roundsrc  = (int*)alloc((size_t)MAXR * EE * 4);
    int* eidx      = (int*)alloc((size_t)EE * 4);
    int* xlist     = (int*)alloc((size_t)EE * 4);
    int* xsrc      = (int*)alloc((size_t)EE * 4);
    int* tx        = (int*)alloc((size_t)TSTEPS * (EE / 3 + 256) * 4);
    int* ulist     = (int*)alloc((size_t)NN * 4);
    int* nidx      = (int*)alloc((size_t)NN * 4);
    us* te_bf    = (us*)alloc((size_t)EE * 128 * 2);
    us* nf_bf    = (us*)alloc((size_t)NN * 256 * 2);
    us* ea_bf    = (us*)alloc((size_t)EE * 128 * 2);
    us* xh       = (us*)alloc((size_t)NN * 256 * 2);   // slist -> xpart_c -> hc
    float* memb  = (float*)alloc((size_t)NN * 256 * 4);
    us* memb_bf  = (us*)alloc((size_t)NN * 256 * 2);
    us* Wt_x    = (us*)alloc((size_t)256 * 512 * 2);
    us* Wt_a    = (us*)alloc((size_t)256 * 256 * 2);
    us* Wt_m2   = (us*)alloc((size_t)256 * 256 * 2);
    us* Wt_gate = (us*)alloc((size_t)1024 * 512 * 2);
    us* Wt_g    = (us*)alloc((size_t)256 * 512 * 2);
    us* Wt_e    = (us*)alloc((size_t)256 * 256 * 2);
    us* Wt_c    = (us*)alloc((size_t)128 * 256 * 2);
    us* Wk_a    = (us*)alloc((size_t)256 * 256 * 2);   // k-major bf16 (tail walker)
    us* Wk_m2   = (us*)alloc((size_t)256 * 256 * 2);
    us* Wk_ih   = (us*)alloc((size_t)256 * 768 * 2 * 2); // interleaved (Wi,Wh) pairs
    float* gvec  = (float*)alloc(256 * 4);
    float* sdot  = (float*)alloc((size_t)NN * 4);
    float* ddot  = (float*)alloc((size_t)NN * 4);
    float* edot  = (float*)alloc((size_t)EE * 4);
    float* logit = (float*)alloc((size_t)EE * 4);
    float* alpha = (float*)alloc((size_t)EE * 4);
    unsigned* mx = (unsigned*)alloc((size_t)NN * 4);
    float* denom = (float*)alloc((size_t)NN * 4);
    // zeroed mask zone (one memset): needed | uneed | scnt
    int* needed  = (int*)alloc((size_t)NN * 4);
    int* uneed   = (int*)alloc((size_t)NN * 4);
    int* scnt    = (int*)alloc((size_t)NN * 4);
    char* zone_end = base + off;

    size_t region = (ws_size > off + 4096) ? (ws_size - off - 4096) : 0;
    long capL = (long)(region / 3584);
    int CAPR = (int)(capL < 0 ? 0 : capL);
    CAPR = (CAPR / 128) * 128;
    if (CAPR > 28160) CAPR = 28160;
    if (CAPR < 1280) return;   // ws too small (visible failure)
    us* xbuf_bf  = (us*)alloc((size_t)CAPR * 256 * 2);
    us* msg_bf   = (us*)alloc((size_t)CAPR * 256 * 2);
    us* hprev_c  = (us*)alloc((size_t)CAPR * 256 * 2);
    us* gates_bf = (us*)alloc((size_t)CAPR * 1024 * 2);
    if (off > ws_size) return;

    unsigned* tm = (unsigned*)&roundcnt[32];
    int* necnt   = &roundcnt[33];
    int* ucnt    = &roundcnt[34];
    int* xcnt    = &roundcnt[35];
    // bucket-sort scratch aliases roundx (dead until k_chain)
    int* hist  = roundx;
    int* hcur  = roundx + NB;
    int* hbase = roundx + 2 * NB;
    int* blist = roundx + 3 * NB;
    // aliases in xh: slist (until k_chain) -> xpart_c (until tails) -> hc (after)
    int* slist = (int*)xh;
    us* xpart_c = xh;
    us* hc = xh;
    us* ef_c = nf_bf;                  // nf_bf dead after h-GEMM
    float* outb = memb;                // f32 mem dead post-scan
    us* pe_bf = te_bf;                 // te dead after ef GEMM
    float* c1 = (float*)(te_bf + (size_t)PP * 256);

    const dim3 B(256);
    const int gE = (EE + 255) / 256;
    const int gN = (NN + 255) / 256;

    hipMemsetAsync(roundcnt, 0, 64 * 4, stream);
    hipMemsetAsync(hist, 0, (size_t)2 * NB * 4, stream);                  // hist + hcur
    hipMemsetAsync(needed, 0, (size_t)(zone_end - (char*)needed), stream);
    hipMemsetAsync(Wt_gate, 0, (size_t)1024 * 512 * 2, stream);           // zero-pad for g2i/g2h halves

    // fused: needed-mask (first 16 blocks) + hist/slist/tmax prep
    k_prep<<<16 + gE, B, 0, stream>>>(pm, needed, t, src, hist, scnt, slist, tm);
    k_elist<<<gE, B, 0, stream>>>(src, dst, needed, necnt, eidx, uneed);
    k_ulist<<<gN, B, 0, stream>>>(uneed, ucnt, ulist, nidx);

    k_scanone<<<1, B, 0, stream>>>(hist, hbase);
    k_bscatter<<<gE, B, 0, stream>>>(t, hbase, hcur, blist);
    k_rank2<<<gE, B, 0, stream>>>(t, hbase, hist, blist, rank);
    k_chain<<<gE, B, 0, stream>>>(src, rank, scnt, slist, uneed, roundcnt, roundx, roundsrc,
                                  xcnt, xlist, xsrc);

    k_zcvt<<<1024, B, 0, stream>>>(ucnt, ulist, nf, nf_bf, memb, memb_bf);
    k_convL2<<<1024, B, 0, stream>>>(xcnt, xlist, necnt, eidx, t, wt, bt, te_bf, ea, ea_bf);

    // k-major bf16 weight copies + interleaved (Wi,Wh) pairs for the tail walker
    {
        int na4 = 256 * 256 / 4, nb4 = 256 * 256 / 4, nih = 256 * 768;
        int tot = na4 + nb4 + nih;
        k_wkflat<<<(tot + 255) / 256, B, 0, stream>>>(
            Wm1 + (size_t)256 * 256, Wk_a, na4, Wm2, Wk_m2, nb4, Wi, Wh, Wk_ih, nih);
    }

    // tiled weight transposes + gvec; Wt_gate = [Wi;Wh | g2i(Wi,0) | g2h(0,Wh)] (1024 x 512)
    {
        WtA wa;
        int o = 0;
        auto set = [&](int i, const float* W, us* dstp, int K, int N, int ld, int koff, int Ktot) {
            wa.d[i] = WtD{W, dstp, K, N, ld, koff, Ktot, o};
            o += (K >> 5) * (N >> 5);
        };
        set(0, Wm1, Wt_x, 256, 256, 256, 0, 512);
        set(1, Wm1 + (size_t)512 * 256, Wt_x, 128, 256, 256, 256, 512);
        set(2, Wm1 + (size_t)640 * 256, Wt_x, 128, 256, 256, 384, 512);
        set(3, Wm1 + (size_t)256 * 256, Wt_a, 256, 256, 256, 0, 256);
        set(4, Wm2, Wt_m2, 256, 256, 256, 0, 256);
        set(5, Wi, Wt_gate, 256, 512, 768, 0, 512);
        set(6, Wh, Wt_gate, 256, 512, 768, 256, 512);
        set(7, Wi + 512, Wt_gate + (size_t)512 * 512, 256, 256, 768, 0, 512);
        set(8, Wh + 512, Wt_gate + (size_t)768 * 512, 256, 256, 768, 256, 512);
        set(9, Wg, Wt_g, 512, 256, 256, 0, 512);
        set(10, We, Wt_e, 256, 256, 256, 0, 256);
        set(11, Wc1, Wt_c, 256, 128, 128, 0, 256);
        wa.ntiles = o;
        k_wt2<<<o + 1, B, 0, stream>>>(wa, tm, wt, bt, Wg, gvec);
    }

    // xpart (compact) = bm1 + nf[xsrc]@Wm1[0:256] + ea[xlist]@.. + te[xlist]@..
    const int gxE = (EE + 127) / 128;
    k_mgemm<<<dim3(gxE, 4), B, 0, stream>>>(nf_bf, 256, xsrc, ea_bf, 128, xlist,
        te_bf, 128, xlist, Wt_x, 512, 512, bm1, nullptr, nullptr,
        nullptr, xpart_c, 256, EE, xcnt, 0, 0, 0);

    // chain rounds 0..1: msg GEMM + fused gate GEMM + elementwise gate
    for (int j = 0; j < TANCH; ++j) {
        int bound = EE / 4;
        for (int cb = 0; cb < bound; cb += CAPR) {
            int m = bound - cb; if (m > CAPR) m = CAPR;
            int gx = (m + 127) / 128;
            const int* rx = roundx + (size_t)j * EE + cb;
            const int* rs = roundsrc + (size_t)j * EE + cb;
            if (j == 0) {
                k_mgemm<<<dim3(gx, 4), B, 0, stream>>>(xpart_c, 256, rx, nullptr, 0, nullptr,
                    nullptr, 0, nullptr, Wt_m2, 256, 256, bm2, nullptr, nullptr,
                    nullptr, msg_bf, 256, m, roundcnt + j, cb, 1, 1);
                k_mgemm<<<dim3(gx, 16), B, 0, stream>>>(msg_bf, 256, nullptr, nullptr, 0, nullptr,
                    nullptr, 0, nullptr, Wt_gate, 256, 512, nullptr, nullptr, nullptr,
                    nullptr, gates_bf, 1024, m, roundcnt + j, cb, 0, 0);
            } else {
                k_hgather<<<(m * 64 + 255) / 256, B, 0, stream>>>(roundcnt + j, cb, m, rs, memb_bf, hprev_c);
                k_mgemm<<<dim3(gx, 4), B, 0, stream>>>(hprev_c, 256, nullptr, nullptr, 0, nullptr,
                    nullptr, 0, nullptr, Wt_a, 256, 256, nullptr, xpart_c, rx,
                    nullptr, xbuf_bf, 256, m, roundcnt + j, cb, 1, 0);
                k_mgemm<<<dim3(gx, 4), B, 0, stream>>>(xbuf_bf, 256, nullptr, nullptr, 0, nullptr,
                    nullptr, 0, nullptr, Wt_m2, 256, 256, bm2, nullptr, nullptr,
                    nullptr, msg_bf, 256, m, roundcnt + j, cb, 1, 0);
                k_mgemm<<<dim3(gx, 16), B, 0, stream>>>(msg_bf, 256, nullptr, hprev_c, 256, nullptr,
                    nullptr, 0, nullptr, Wt_gate, 512, 512, nullptr, nullptr, nullptr,
                    nullptr, gates_bf, 1024, m, roundcnt + j, cb, 0, 0);
            }
            k_gate<<<2048, B, 0, stream>>>(roundcnt + j, cb, m, rs, gates_bf, bi, bh, memb, memb_bf);
        }
    }
    // tail rounds TANCH..11: fixed-grid chain walker (grid-stride over chains)
    k_tbuild<<<(EE / 3 + 255) / 256, B, 0, stream>>>(roundcnt, roundx, roundsrc, tx);
    k_tailchain<<<TGRID, dim3(1024), 0, stream>>>(roundcnt, roundsrc, tx, xpart_c,
                                                  Wk_a, Wk_m2, Wk_ih,
                                                  bm2, bi, bh, memb, memb_bf);

    k_zout<<<(PP * 64 + 255) / 256, B, 0, stream>>>(pm, outb, denom, mx);

    // h (compact U rows) = [nf | mem]@Wg + gvec bias
    const int gxN = (NN + 127) / 128;
    k_mgemm<<<dim3(gxN, 4), B, 0, stream>>>(nf_bf, 256, ulist, memb_bf, 256, ulist,
        nullptr, 0, nullptr, Wt_g, 512, 512, gvec, nullptr, nullptr,
        nullptr, hc, 256, NN, ucnt, 0, 0, 0);

    // ef (compact needed edges) = [ea | te](eidx) @ We
    k_mgemm<<<dim3(gxE, 4), B, 0, stream>>>(ea_bf, 128, eidx, te_bf, 128, eidx,
        nullptr, 0, nullptr, Wt_e, 256, 256, nullptr, nullptr, nullptr,
        nullptr, ef_c, 256, EE, necnt, 0, 0, 0);

    k_dots<<<2048, B, 0, stream>>>(hc, ef_c, ucnt, necnt, a_src, a_dst, a_e, sdot, ddot, edot);

    k_logitc<<<gE, B, 0, stream>>>(necnt, eidx, nidx, sdot, ddot, edot, src, dst, logit, mx);
    k_alphac<<<gE, B, 0, stream>>>(necnt, eidx, logit, dst, mx, alpha, denom);
    k_scatc<<<1024, B, 0, stream>>>(necnt, eidx, nidx, alpha, src, dst, hc, ef_c, outb);

    k_pe<<<PP, B, 0, stream>>>(pm, outb, denom, pe_bf);
    k_mgemm<<<dim3((PP + 127) / 128, 2), B, 0, stream>>>(pe_bf, 256, nullptr, nullptr, 0, nullptr,
        nullptr, 0, nullptr, Wt_c, 256, 256, bc1, nullptr, nullptr,
        c1, nullptr, 128, PP, nullptr, 0, 1, 0);
    k_final<<<(PP + 3) / 4, B, 0, stream>>>(c1, Wc2, bc2, outp);
}

// Round 17
// 431.284 us; speedup vs baseline: 1.1643x; 1.1643x over previous
//
#include <hip/hip_runtime.h>

#define NN 50000
#define EE 40000
#define PP 4096
#define MAXR 12
#define SCAP 16
#define NB 8192
#define TANCH 2
#define TSTEPS 10
#define TGRID 512

typedef unsigned short us;
typedef __attribute__((ext_vector_type(8))) short bf8v;
typedef __attribute__((ext_vector_type(4))) float f4v;

__device__ __forceinline__ us f2b(float x) {
    unsigned u = __float_as_uint(x);
    u = (u + 0x7fffu + ((u >> 16) & 1u)) >> 16;
    return (us)u;
}
__device__ __forceinline__ float b2f(us h) {
    return __uint_as_float(((unsigned)h) << 16);
}
__device__ __forceinline__ unsigned fkey(float f) {
    unsigned u = __float_as_uint(f);
    return (u & 0x80000000u) ? ~u : (u | 0x80000000u);
}
__device__ __forceinline__ float funkey(unsigned k) {
    unsigned u = (k & 0x80000000u) ? (k & 0x7fffffffu) : ~k;
    return __uint_as_float(u);
}
__device__ __forceinline__ int bucket_of(float tv) {
    int b = (int)(tv * 8192.0f);
    if (b < 0) b = 0;
    if (b > NB - 1) b = NB - 1;
    return b;
}
__device__ __forceinline__ unsigned relu2bf(unsigned u) {
    unsigned lo = (u & 0x8000u) ? 0u : (u & 0xFFFFu);
    unsigned hi = (u & 0x80000000u) ? 0u : (u & 0xFFFF0000u);
    return lo | hi;
}

// ---------------- needed nodes / edges / U-set ----------------

__global__ void k_elist(const int* __restrict__ src, const int* __restrict__ dst,
                        const int* __restrict__ needed, int* __restrict__ necnt,
                        int* __restrict__ eidx, int* __restrict__ uneed)
{
    __shared__ int lc, lb;
    if (threadIdx.x == 0) lc = 0;
    __syncthreads();
    int e = blockIdx.x * 256 + threadIdx.x;
    int slot = -1;
    if (e < EE && needed[dst[e]]) {
        slot = atomicAdd(&lc, 1);
        uneed[dst[e]] = 1;
        uneed[src[e]] = 1;
    }
    __syncthreads();
    if (threadIdx.x == 0 && lc) lb = atomicAdd(necnt, lc);
    __syncthreads();
    if (slot >= 0) eidx[lb + slot] = e;
}

__global__ void k_ulist(const int* __restrict__ uneed, int* __restrict__ ucnt,
                        int* __restrict__ ulist, int* __restrict__ nidx)
{
    __shared__ int lc, lb;
    if (threadIdx.x == 0) lc = 0;
    __syncthreads();
    int n = blockIdx.x * 256 + threadIdx.x;
    int slot = -1;
    if (n < NN && uneed[n]) slot = atomicAdd(&lc, 1);
    __syncthreads();
    if (threadIdx.x == 0 && lc) lb = atomicAdd(ucnt, lc);
    __syncthreads();
    if (slot >= 0) { ulist[lb + slot] = n; nidx[n] = lb + slot; }
}

// ---------------- ordering (k_need fused in as first 16 blocks) ----------------

__global__ __launch_bounds__(256) void k_prep(const int* __restrict__ pm, int* __restrict__ needed,
                                              const float* __restrict__ t, const int* __restrict__ src,
                                              int* __restrict__ hist, int* __restrict__ scnt,
                                              int* __restrict__ slist, unsigned* __restrict__ tm)
{
    if (blockIdx.x < 16) {
        int i = blockIdx.x * 256 + threadIdx.x;
        if (i < PP) needed[pm[i]] = 1;
        return;
    }
    int e = (blockIdx.x - 16) * 256 + threadIdx.x;
    float v = 0.f;
    if (e < EE) {
        float tv = t[e];
        v = tv;
        atomicAdd(&hist[bucket_of(tv)], 1);
        int s = src[e];
        int slot = atomicAdd(&scnt[s], 1);
        if (slot < SCAP) slist[s * SCAP + slot] = e;
    }
#pragma unroll
    for (int o = 32; o > 0; o >>= 1) v = fmaxf(v, __shfl_xor(v, o));
    if ((threadIdx.x & 63) == 0) atomicMax(tm, fkey(v));
}

// single-block exclusive prefix scan over NB=8192 bins
__global__ __launch_bounds__(256) void k_scanone(const int* __restrict__ hist, int* __restrict__ hbase)
{
    __shared__ int tot[256];
    int t = threadIdx.x;
    int base = t * (NB / 256);
    int loc[NB / 256];
    int s = 0;
#pragma unroll
    for (int i = 0; i < NB / 256; ++i) { loc[i] = s; s += hist[base + i]; }
    tot[t] = s;
    __syncthreads();
    for (int o = 1; o < 256; o <<= 1) {
        int x = (t >= o) ? tot[t - o] : 0;
        __syncthreads();
        tot[t] += x;
        __syncthreads();
    }
    int off = tot[t] - s;   // exclusive
#pragma unroll
    for (int i = 0; i < NB / 256; ++i) hbase[base + i] = loc[i] + off;
}

__global__ void k_bscatter(const float* __restrict__ t, const int* __restrict__ hbase,
                           int* __restrict__ hcur, int* __restrict__ blist)
{
    int e = blockIdx.x * 256 + threadIdx.x;
    if (e >= EE) return;
    int b = bucket_of(t[e]);
    int p = hbase[b] + atomicAdd(&hcur[b], 1);
    blist[p] = e;
}

__global__ void k_rank2(const float* __restrict__ t, const int* __restrict__ hbase,
                        const int* __restrict__ hist, const int* __restrict__ blist,
                        int* __restrict__ rank)
{
    int e = blockIdx.x * 256 + threadIdx.x;
    if (e >= EE) return;
    float te_ = t[e];
    int b = bucket_of(te_);
    int base = hbase[b], cnt = hist[b];
    int r = base;
    for (int i = 0; i < cnt; ++i) {
        int j = blist[base + i];
        float tj = t[j];
        r += (tj < te_ || (tj == te_ && j < e)) ? 1 : 0;
    }
    rank[e] = r;
}

// chain decomposition (filtered) + round insert + xpart compaction
__global__ void k_chain(const int* __restrict__ src, const int* __restrict__ rank,
                        const int* __restrict__ scnt, const int* __restrict__ slist,
                        const int* __restrict__ uneed,
                        int* __restrict__ roundcnt, int* __restrict__ roundx, int* __restrict__ roundsrc,
                        int* __restrict__ xcnt, int* __restrict__ xlist, int* __restrict__ xsrc)
{
    __shared__ int lcnt[MAXR];
    __shared__ int lbase[MAXR];
    __shared__ int xl, xb;
    int tid = threadIdx.x;
    if (tid < MAXR) lcnt[tid] = 0;
    if (tid == 0) xl = 0;
    __syncthreads();
    int e = blockIdx.x * 256 + tid;
    int pos = -1, slot = 0, xs = 0, ssave = 0;
    if (e < EE && uneed[src[e]]) {
        int s = src[e];
        int c = scnt[s]; if (c > SCAP) c = SCAP;
        int re = rank[e], be = re / 200;
        bool r_e = true;
        for (int i = 0; i < c; ++i) {
            int rj = rank[slist[s * SCAP + i]];
            if (rj / 200 == be && rj > re) { r_e = false; break; }
        }
        if (r_e) {
            int p = 0;
            for (int i = 0; i < c; ++i) {
                int rj = rank[slist[s * SCAP + i]];
                if (rj >= re) continue;
                int bj = rj / 200;
                bool r_j = true;
                for (int k2 = 0; k2 < c; ++k2) {
                    int rj2 = rank[slist[s * SCAP + k2]];
                    if (rj2 / 200 == bj && rj2 > rj) { r_j = false; break; }
                }
                p += r_j ? 1 : 0;
            }
            if (p < MAXR) { pos = p; ssave = s; slot = atomicAdd(&lcnt[p], 1); xs = atomicAdd(&xl, 1); }
        }
    }
    __syncthreads();
    if (tid < MAXR && lcnt[tid]) lbase[tid] = atomicAdd(&roundcnt[tid], lcnt[tid]);
    if (tid == 0 && xl) xb = atomicAdd(xcnt, xl);
    __syncthreads();
    if (pos >= 0) {
        int xr = xb + xs;
        xlist[xr] = e;
        xsrc[xr] = ssave;
        size_t o = (size_t)pos * EE + lbase[pos] + slot;
        roundx[o] = xr;
        roundsrc[o] = ssave;
    }
}

// ---------------- targeted zero / conversions ----------------

// fused: zero memb/memb_bf + convert nf rows at U nodes
__global__ void k_zcvt(const int* __restrict__ ucnt, const int* __restrict__ ulist,
                       const float* __restrict__ nf, us* __restrict__ nf_bf,
                       float* __restrict__ memb, us* __restrict__ memb_bf)
{
    int total = *ucnt * 64;
    for (int i = blockIdx.x * 256 + threadIdx.x; i < total; i += gridDim.x * 256) {
        int n = ulist[i >> 6], q = i & 63;
        reinterpret_cast<float4*>(memb + (size_t)n * 256)[q] = make_float4(0.f, 0.f, 0.f, 0.f);
        reinterpret_cast<ushort4*>(memb_bf + (size_t)n * 256)[q] = make_ushort4(0, 0, 0, 0);
        float4 v = reinterpret_cast<const float4*>(nf + (size_t)n * 256)[q];
        ushort4 o; o.x = f2b(v.x); o.y = f2b(v.y); o.z = f2b(v.z); o.w = f2b(v.w);
        reinterpret_cast<ushort4*>(nf_bf + (size_t)n * 256)[q] = o;
    }
}

// te (sin) + ea conversion over BOTH edge lists in one launch
__global__ void k_convL2(const int* __restrict__ xcnt, const int* __restrict__ xlist,
                         const int* __restrict__ necnt, const int* __restrict__ eidx,
                         const float* __restrict__ t, const float* __restrict__ w,
                         const float* __restrict__ b, us* __restrict__ te,
                         const float* __restrict__ ea, us* __restrict__ ea_bf)
{
    int t1 = *xcnt * 32, t2 = *necnt * 32;
    int total = t1 + t2;
    for (int i = blockIdx.x * 256 + threadIdx.x; i < total; i += gridDim.x * 256) {
        int ii = i;
        const int* lst = xlist;
        if (ii >= t1) { ii -= t1; lst = eidx; }
        int e = lst[ii >> 5], q = (ii & 31) * 4;
        float tv = t[e];
        ushort4 ot;
        ot.x = f2b(sinf(tv * w[q] + b[q]));
        ot.y = f2b(sinf(tv * w[q + 1] + b[q + 1]));
        ot.z = f2b(sinf(tv * w[q + 2] + b[q + 2]));
        ot.w = f2b(sinf(tv * w[q + 3] + b[q + 3]));
        *reinterpret_cast<ushort4*>(te + (size_t)e * 128 + q) = ot;
        float4 v = *reinterpret_cast<const float4*>(ea + (size_t)e * 128 + q);
        ushort4 oa; oa.x = f2b(v.x); oa.y = f2b(v.y); oa.z = f2b(v.z); oa.w = f2b(v.w);
        *reinterpret_cast<ushort4*>(ea_bf + (size_t)e * 128 + q) = oa;
    }
}

__global__ void k_zout(const int* __restrict__ pm, float* __restrict__ outb,
                       float* __restrict__ denom, unsigned* __restrict__ mx)
{
    int i = blockIdx.x * 256 + threadIdx.x;
    int p = i >> 6, q = i & 63;
    if (p >= PP) return;
    int n = pm[p];
    reinterpret_cast<float4*>(outb + (size_t)n * 256)[q] = make_float4(0.f, 0.f, 0.f, 0.f);
    if (q == 0) { denom[n] = 0.f; mx[n] = 0u; }
}

// k-major bf16 weight copies + interleaved (Wi,Wh) pair buffer for the tail walker
__global__ void k_wkflat(const float* __restrict__ sa, us* __restrict__ da, int na4,
                         const float* __restrict__ sb, us* __restrict__ db, int nb4,
                         const float* __restrict__ Wi, const float* __restrict__ Wh,
                         us* __restrict__ Wk_ih, int nih)
{
    int i = blockIdx.x * 256 + threadIdx.x;
    int j = i;
    if (j < na4) {
        float4 v = reinterpret_cast<const float4*>(sa)[j];
        ushort4 o; o.x = f2b(v.x); o.y = f2b(v.y); o.z = f2b(v.z); o.w = f2b(v.w);
        reinterpret_cast<ushort4*>(da)[j] = o;
        return;
    }
    j -= na4;
    if (j < nb4) {
        float4 v = reinterpret_cast<const float4*>(sb)[j];
        ushort4 o; o.x = f2b(v.x); o.y = f2b(v.y); o.z = f2b(v.z); o.w = f2b(v.w);
        reinterpret_cast<ushort4*>(db)[j] = o;
        return;
    }
    j -= nb4;
    if (j < nih) {
        unsigned lo = (unsigned)f2b(Wi[j]);
        unsigned hi = (unsigned)f2b(Wh[j]);
        reinterpret_cast<unsigned*>(Wk_ih)[j] = lo | (hi << 16);
    }
}

// ---------------- tiled weight transpose (+ gvec block) ----------------

struct WtD { const float* W; us* dst; int K, N, ld, koff, Ktot, toff; };
struct WtA { WtD d[12]; int ntiles; };

__global__ __launch_bounds__(256) void k_wt2(WtA wa, const unsigned* __restrict__ tm,
                                             const float* __restrict__ wt, const float* __restrict__ bt,
                                             const float* __restrict__ Wg, float* __restrict__ gvec)
{
    if ((int)blockIdx.x == wa.ntiles) {
        __shared__ float sv[128];
        int c = threadIdx.x;
        float tmax = funkey(*tm);
        if (c < 128) sv[c] = sinf(tmax * wt[c] + bt[c]);
        __syncthreads();
        float acc = 0.f;
        for (int k = 0; k < 128; ++k) acc += sv[k] * Wg[(size_t)(512 + k) * 256 + c];
        gvec[c] = acc;
        return;
    }
    int bid = blockIdx.x;
    int di = 0;
#pragma unroll
    for (int i = 1; i < 12; ++i) if (bid >= wa.d[i].toff) di = i;
    WtD d = wa.d[di];
    int tt = bid - d.toff;
    int tn = d.N >> 5;
    int k0 = (tt / tn) << 5, n0 = (tt % tn) << 5;
    __shared__ float ld[32][33];
    int tx = threadIdx.x & 31, ty = threadIdx.x >> 5;
#pragma unroll
    for (int i = 0; i < 4; ++i)
        ld[ty + 8 * i][tx] = d.W[(size_t)(k0 + ty + 8 * i) * d.ld + n0 + tx];
    __syncthreads();
#pragma unroll
    for (int i = 0; i < 4; ++i) {
        int n = n0 + ty + 8 * i;
        d.dst[(size_t)n * d.Ktot + d.koff + k0 + tx] = f2b(ld[tx][ty + 8 * i]);
    }
}

// ---------------- MFMA GEMM ----------------
__global__ __launch_bounds__(256) void k_mgemm(
    const us* __restrict__ A1, int K1, const int* __restrict__ idx1,
    const us* __restrict__ A2, int K2, const int* __restrict__ idx2,
    const us* __restrict__ A3, int K3, const int* __restrict__ idx3,
    const us* __restrict__ Wt, int Kloop, int ldw,
    const float* __restrict__ bias,
    const us* __restrict__ Cin, const int* __restrict__ cidx,
    float* __restrict__ outF, us* __restrict__ outB, int ldc,
    int Mhost, const int* __restrict__ mdev, int mbase, int relu, int relua)
{
    int M = Mhost;
    if (mdev) {
        int avail = *mdev - mbase;
        if (avail < 0) avail = 0;
        if (avail < M) M = avail;
    }
    const int row0 = blockIdx.x * 128;
    if (row0 >= M) return;
    const int col0 = blockIdx.y * 64;

    __shared__ us As[128 * 64];
    __shared__ us Bs[64 * 64];

    const int tid = threadIdx.x;
    const int l = tid & 63;
    const int wv = tid >> 6;

    f4v acc[2][4];
#pragma unroll
    for (int i = 0; i < 2; ++i)
#pragma unroll
        for (int j = 0; j < 4; ++j) acc[i][j] = (f4v){0.f, 0.f, 0.f, 0.f};

    for (int k0 = 0; k0 < Kloop; k0 += 64) {
#pragma unroll
        for (int it = 0; it < 4; ++it) {
            int idx = tid + it * 256;
            int r = idx >> 3, q = idx & 7;
            int gk = k0 + q * 8;
            int grow = row0 + r;
            uint4 v = make_uint4(0u, 0u, 0u, 0u);
            if (grow < M) {
                const us* sp; int st, krel, ar = grow;
                if (gk < K1) {
                    sp = A1; st = K1; krel = gk;
                    if (idx1) ar = idx1[ar];
                } else if (gk < K1 + K2) {
                    sp = A2; st = K2; krel = gk - K1;
                    if (idx2) ar = idx2[ar];
                } else {
                    sp = A3; st = K3; krel = gk - K1 - K2;
                    if (idx3) ar = idx3[ar];
                }
                v = *reinterpret_cast<const uint4*>(sp + (size_t)ar * st + krel);
                if (relua) { v.x = relu2bf(v.x); v.y = relu2bf(v.y); v.z = relu2bf(v.z); v.w = relu2bf(v.w); }
            }
            *reinterpret_cast<uint4*>(As + r * 64 + ((q ^ (r & 7)) << 3)) = v;
        }
#pragma unroll
        for (int it = 0; it < 2; ++it) {
            int idx = tid + it * 256;
            int c = idx >> 3, q = idx & 7;
            uint4 v = *reinterpret_cast<const uint4*>(Wt + (size_t)(col0 + c) * ldw + k0 + q * 8);
            *reinterpret_cast<uint4*>(Bs + c * 64 + ((q ^ (c & 7)) << 3)) = v;
        }
        __syncthreads();
#pragma unroll
        for (int ks = 0; ks < 2; ++ks) {
            bf8v af[2], bfr[4];
#pragma unroll
            for (int mf = 0; mf < 2; ++mf) {
                int r = wv * 32 + mf * 16 + (l & 15);
                int q = ks * 4 + (l >> 4);
                af[mf] = *reinterpret_cast<const bf8v*>(As + r * 64 + ((q ^ (r & 7)) << 3));
            }
#pragma unroll
            for (int nf = 0; nf < 4; ++nf) {
                int c = nf * 16 + (l & 15);
                int q = ks * 4 + (l >> 4);
                bfr[nf] = *reinterpret_cast<const bf8v*>(Bs + c * 64 + ((q ^ (c & 7)) << 3));
            }
#pragma unroll
            for (int mf = 0; mf < 2; ++mf)
#pragma unroll
                for (int nf = 0; nf < 4; ++nf)
                    acc[mf][nf] = __builtin_amdgcn_mfma_f32_16x16x32_bf16(af[mf], bfr[nf], acc[mf][nf], 0, 0, 0);
        }
        __syncthreads();
    }

#pragma unroll
    for (int mf = 0; mf < 2; ++mf) {
#pragma unroll
        for (int rr = 0; rr < 4; ++rr) {
            int row = row0 + wv * 32 + mf * 16 + ((l >> 4) * 4) + rr;
            if (row >= M) continue;
            size_t crow = 0;
            if (Cin) crow = (size_t)(cidx ? cidx[row] : row) * ldc;
#pragma unroll
            for (int nf = 0; nf < 4; ++nf) {
                int col = col0 + nf * 16 + (l & 15);
                float v = acc[mf][nf][rr];
                if (bias) v += bias[col];
                if (Cin) v += b2f(Cin[crow + col]);
                if (relu) v = fmaxf(v, 0.f);
                if (outF) outF[(size_t)row * ldc + col] = v;
                if (outB) outB[(size_t)row * ldc + col] = f2b(v);
            }
        }
    }
}

// ---------------- scan helpers ----------------

__global__ void k_hgather(const int* __restrict__ cnt, int cb, int m, const int* __restrict__ rs,
                          const us* __restrict__ mem_bf, us* __restrict__ hprev)
{
    int idx = blockIdx.x * 256 + threadIdx.x;
    int i = idx >> 6, q = idx & 63;
    int avail = *cnt - cb;
    if (avail > m) avail = m;
    if (i >= avail) return;
    int s = rs[i];
    reinterpret_cast<ushort4*>(hprev + (size_t)i * 256)[q] =
        reinterpret_cast<const ushort4*>(mem_bf + (size_t)s * 256)[q];
}

// grid-stride over rows (fixed grid)
__global__ void k_gate(const int* __restrict__ cnt, int cb, int m, const int* __restrict__ rs,
                       const us* __restrict__ gates, const float* __restrict__ bi,
                       const float* __restrict__ bh,
                       float* __restrict__ mem, us* __restrict__ mem_bf)
{
    int avail = *cnt - cb;
    if (avail > m) avail = m;
    int c = threadIdx.x;
    for (int i = blockIdx.x; i < avail; i += gridDim.x) {
        int s = rs[i];
        float hp = mem[(size_t)s * 256 + c];
        const us* g = gates + (size_t)i * 1024;
        float g0 = b2f(g[c]) + bi[c] + bh[c];
        float g1 = b2f(g[256 + c]) + bi[256 + c] + bh[256 + c];
        float g2i = b2f(g[512 + c]) + bi[512 + c];
        float g2h = b2f(g[768 + c]) + bh[512 + c];
        float r = 1.f / (1.f + expf(-g0));
        float z = 1.f / (1.f + expf(-g1));
        float n = tanhf(g2i + r * g2h);
        float hnew = (1.f - z) * n + z * hp;
        mem[(size_t)s * 256 + c] = hnew;
        mem_bf[(size_t)s * 256 + c] = f2b(hnew);
    }
}

// build per-source tail chains anchored at round TANCH
__global__ void k_tbuild(const int* __restrict__ roundcnt, const int* __restrict__ roundx,
                         const int* __restrict__ roundsrc, int* __restrict__ tx)
{
    int i = blockIdx.x * 256 + threadIdx.x;
    if (i >= roundcnt[TANCH]) return;
    int s = roundsrc[(size_t)TANCH * EE + i];
    tx[i * TSTEPS + 0] = roundx[(size_t)TANCH * EE + i];
#pragma unroll
    for (int k = 1; k < TSTEPS; ++k) tx[i * TSTEPS + k] = -1;
    for (int j = TANCH + 1; j < MAXR; ++j) {
        int cj = roundcnt[j];
        for (int m2 = 0; m2 < cj; ++m2) {
            if (roundsrc[(size_t)j * EE + m2] == s) {
                tx[i * TSTEPS + (j - TANCH)] = roundx[(size_t)j * EE + m2];
                break;
            }
        }
    }
}

// fixed-grid chain walker (round-15 exact phase structure: known-good 111us;
// round-16's k-pair variant regressed 70% -- reverted).
__global__ __launch_bounds__(1024) void k_tailchain(
    const int* __restrict__ roundcnt, const int* __restrict__ roundsrc, const int* __restrict__ tx,
    const us* __restrict__ xpart_c, const us* __restrict__ Wk_a, const us* __restrict__ Wk_m2,
    const us* __restrict__ Wk_ih, const float* __restrict__ bm2,
    const float* __restrict__ bi, const float* __restrict__ bh,
    float* __restrict__ mem, us* __restrict__ mem_bf)
{
    const int cnt = roundcnt[TANCH];
    const int tid = threadIdx.x;
    const int c = tid & 255;
    const int p = tid >> 8;          // 0..3 (init/gate lanes use p==0)
    const int c2 = (tid & 127) * 2;  // channel pair for phases 1/2
    const int kp = tid >> 7;         // 0..7 k-eighth
    __shared__ float hb[256];
    __shared__ float xv[256];
    __shared__ float msgv[256];
    __shared__ float red[8][256];
    __shared__ float oi[768];
    __shared__ float oh[768];
    for (int i = blockIdx.x; i < cnt; i += gridDim.x) {
        int s = roundsrc[(size_t)TANCH * EE + i];
        float hp = 0.f;
        if (p == 0) { hp = mem[(size_t)s * 256 + c]; hb[c] = hp; }
        __syncthreads();
        for (int k = 0; k < TSTEPS; ++k) {
            int xr = tx[i * TSTEPS + k];
            if (xr < 0) break;
            // phase1: xv = relu(xpart + hb@Wm1a)
            {
                float a0 = 0.f, a1 = 0.f;
                int k0 = kp * 32;
#pragma unroll 16
                for (int kk = 0; kk < 32; ++kk) {
                    unsigned w = *reinterpret_cast<const unsigned*>(Wk_a + (size_t)(k0 + kk) * 256 + c2);
                    float hv = hb[k0 + kk];
                    a0 += b2f((us)(w & 0xffffu)) * hv;
                    a1 += b2f((us)(w >> 16)) * hv;
                }
                red[kp][c2] = a0;
                red[kp][c2 + 1] = a1;
            }
            __syncthreads();
            if (p == 0) {
                float a = b2f(xpart_c[(size_t)xr * 256 + c]);
#pragma unroll
                for (int r8 = 0; r8 < 8; ++r8) a += red[r8][c];
                xv[c] = fmaxf(a, 0.f);
            }
            __syncthreads();
            // phase2: msg = relu(xv@Wm2 + bm2)
            {
                float a0 = 0.f, a1 = 0.f;
                int k0 = kp * 32;
#pragma unroll 16
                for (int kk = 0; kk < 32; ++kk) {
                    unsigned w = *reinterpret_cast<const unsigned*>(Wk_m2 + (size_t)(k0 + kk) * 256 + c2);
                    float hv = xv[k0 + kk];
                    a0 += b2f((us)(w & 0xffffu)) * hv;
                    a1 += b2f((us)(w >> 16)) * hv;
                }
                red[kp][c2] = a0;
                red[kp][c2 + 1] = a1;
            }
            __syncthreads();
            if (p == 0) {
                float a = bm2[c];
#pragma unroll
                for (int r8 = 0; r8 < 8; ++r8) a += red[r8][c];
                msgv[c] = fmaxf(a, 0.f);
            }
            __syncthreads();
            // phase3: thread j<768: oi[j] = msg@Wi[:,j], oh[j] = hb@Wh[:,j] via interleaved pairs
            if (tid < 768) {
                float ai = 0.f, ah = 0.f;
#pragma unroll 16
                for (int kk = 0; kk < 256; ++kk) {
                    unsigned w = reinterpret_cast<const unsigned*>(Wk_ih)[(size_t)kk * 768 + tid];
                    ai += b2f((us)(w & 0xffffu)) * msgv[kk];
                    ah += b2f((us)(w >> 16)) * hb[kk];
                }
                oi[tid] = ai;
                oh[tid] = ah;
            }
            __syncthreads();
            if (p == 0) {
                float r = 1.f / (1.f + expf(-(oi[c] + oh[c] + bi[c] + bh[c])));
                float z = 1.f / (1.f + expf(-(oi[256 + c] + oh[256 + c] + bi[256 + c] + bh[256 + c])));
                float n = tanhf((oi[512 + c] + bi[512 + c]) + r * (oh[512 + c] + bh[512 + c]));
                hp = (1.f - z) * n + z * hp;
                hb[c] = hp;
            }
            __syncthreads();
        }
        if (p == 0) {
            mem[(size_t)s * 256 + c] = hp;
            mem_bf[(size_t)s * 256 + c] = f2b(hp);
        }
        __syncthreads();
    }
}

// ---------------- attention / head ----------------

// grid-stride over ucnt h-rows + necnt ef-rows (fixed grid; no empty-block churn)
__global__ __launch_bounds__(256) void k_dots(const us* __restrict__ hc, const us* __restrict__ efc,
                                              const int* __restrict__ ucnt, const int* __restrict__ necnt,
                                              const float* __restrict__ v_s, const float* __restrict__ v_d,
                                              const float* __restrict__ v_e,
                                              float* __restrict__ sdot, float* __restrict__ ddot,
                                              float* __restrict__ edot)
{
    int lane = threadIdx.x & 63;
    int sub = threadIdx.x >> 6;
    int u = *ucnt;
    int tot = u + *necnt;
    for (int row = blockIdx.x * 4 + sub; row < tot; row += gridDim.x * 4) {
        if (row < u) {
            ushort4 q = reinterpret_cast<const ushort4*>(hc + (size_t)row * 256)[lane];
            int c = lane * 4;
            float x0 = b2f(q.x), x1 = b2f(q.y), x2 = b2f(q.z), x3 = b2f(q.w);
            float s1 = x0 * v_s[c] + x1 * v_s[c + 1] + x2 * v_s[c + 2] + x3 * v_s[c + 3];
            float s2 = x0 * v_d[c] + x1 * v_d[c + 1] + x2 * v_d[c + 2] + x3 * v_d[c + 3];
#pragma unroll
            for (int o = 32; o > 0; o >>= 1) { s1 += __shfl_xor(s1, o); s2 += __shfl_xor(s2, o); }
            if (lane == 0) { sdot[row] = s1; ddot[row] = s2; }
        } else {
            int i = row - u;
            ushort4 q = reinterpret_cast<const ushort4*>(efc + (size_t)i * 256)[lane];
            int c = lane * 4;
            float s1 = b2f(q.x) * v_e[c] + b2f(q.y) * v_e[c + 1] + b2f(q.z) * v_e[c + 2] + b2f(q.w) * v_e[c + 3];
#pragma unroll
            for (int o = 32; o > 0; o >>= 1) s1 += __shfl_xor(s1, o);
            if (lane == 0) edot[i] = s1;
        }
    }
}

__global__ void k_logitc(const int* __restrict__ necnt, const int* __restrict__ eidx,
                         const int* __restrict__ nidx,
                         const float* __restrict__ sdot, const float* __restrict__ ddot,
                         const float* __restrict__ edot, const int* __restrict__ src,
                         const int* __restrict__ dst, float* __restrict__ logit,
                         unsigned* __restrict__ mx)
{
    int i = blockIdx.x * 256 + threadIdx.x;
    if (i >= *necnt) return;
    int e = eidx[i];
    float l = sdot[nidx[src[e]]] + ddot[nidx[dst[e]]] + edot[i];
    l = (l > 0.f) ? l : 0.2f * l;
    logit[i] = l;
    atomicMax(&mx[dst[e]], fkey(l));
}

__global__ void k_alphac(const int* __restrict__ necnt, const int* __restrict__ eidx,
                         const float* __restrict__ logit, const int* __restrict__ dst,
                         const unsigned* __restrict__ mx, float* __restrict__ alpha,
                         float* __restrict__ denom)
{
    int i = blockIdx.x * 256 + threadIdx.x;
    if (i >= *necnt) return;
    int d = dst[eidx[i]];
    float a = expf(logit[i] - funkey(mx[d]));
    alpha[i] = a;
    atomicAdd(&denom[d], a);
}

// grid-stride over needed edges (fixed grid)
__global__ void k_scatc(const int* __restrict__ necnt, const int* __restrict__ eidx,
                        const int* __restrict__ nidx,
                        const float* __restrict__ alpha, const int* __restrict__ src,
                        const int* __restrict__ dst, const us* __restrict__ hc,
                        const us* __restrict__ efc, float* __restrict__ outb)
{
    int sub = threadIdx.x >> 6;
    int c4 = threadIdx.x & 63;
    int n = *necnt;
    for (int i = blockIdx.x * 4 + sub; i < n; i += gridDim.x * 4) {
        int e = eidx[i];
        float a = alpha[i];
        ushort4 hv = reinterpret_cast<const ushort4*>(hc + (size_t)nidx[src[e]] * 256)[c4];
        ushort4 ev = reinterpret_cast<const ushort4*>(efc + (size_t)i * 256)[c4];
        float* op = outb + (size_t)dst[e] * 256 + c4 * 4;
        atomicAdd(op + 0, a * (b2f(hv.x) + b2f(ev.x)));
        atomicAdd(op + 1, a * (b2f(hv.y) + b2f(ev.y)));
        atomicAdd(op + 2, a * (b2f(hv.z) + b2f(ev.z)));
        atomicAdd(op + 3, a * (b2f(hv.w) + b2f(ev.w)));
    }
}

__global__ void k_pe(const int* __restrict__ pm, const float* __restrict__ outb,
                     const float* __restrict__ denom, us* __restrict__ pe)
{
    int p = blockIdx.x, c = threadIdx.x;
    int n = pm[p];
    pe[(size_t)p * 256 + c] = f2b(outb[(size_t)n * 256 + c] / (denom[n] + 1e-16f));
}

__global__ __launch_bounds__(256) void k_final(const float* __restrict__ c1, const float* __restrict__ Wc2,
                                               const float* __restrict__ bc2, float* __restrict__ out)
{
    int lane = threadIdx.x & 63;
    int row = blockIdx.x * 4 + (threadIdx.x >> 6);
    if (row >= PP) return;
    float s = 0.f;
    for (int c = lane; c < 128; c += 64) s += c1[(size_t)row * 128 + c] * Wc2[c];
#pragma unroll
    for (int off = 32; off > 0; off >>= 1) s += __shfl_xor(s, off);
    if (lane == 0) out[row] = 1.f / (1.f + expf(-(s + bc2[0])));
}

// ---------------- host ----------------

extern "C" void kernel_launch(void* const* d_in, const int* in_sizes, int n_in,
                              void* d_out, int out_size, void* d_ws, size_t ws_size,
                              hipStream_t stream)
{
    (void)in_sizes; (void)n_in; (void)out_size;
    const float* nf    = (const float*)d_in[0];
    const int*   ei    = (const int*)  d_in[1];
    const float* ea    = (const float*)d_in[2];
    const float* t     = (const float*)d_in[3];
    const int*   pm    = (const int*)  d_in[4];
    const float* wt    = (const float*)d_in[5];
    const float* bt    = (const float*)d_in[6];
    const float* Wm1   = (const float*)d_in[7];
    const float* bm1   = (const float*)d_in[8];
    const float* Wm2   = (const float*)d_in[9];
    const float* bm2   = (const float*)d_in[10];
    const float* Wi    = (const float*)d_in[11];
    const float* Wh    = (const float*)d_in[12];
    const float* bi    = (const float*)d_in[13];
    const float* bh    = (const float*)d_in[14];
    const float* Wg    = (const float*)d_in[15];
    const float* We    = (const float*)d_in[16];
    const float* a_src = (const float*)d_in[17];
    const float* a_dst = (const float*)d_in[18];
    const float* a_e   = (const float*)d_in[19];
    const float* Wc1   = (const float*)d_in[20];
    const float* bc1   = (const float*)d_in[21];
    const float* Wc2   = (const float*)d_in[22];
    const float* bc2   = (const float*)d_in[23];
    float* outp = (float*)d_out;
    const int* src = ei;
    const int* dst = ei + EE;

    char* base = (char*)d_ws;
    size_t off = 0;
    auto alloc = [&](size_t bytes) -> void* {
        void* p = base + off;
        off = (off + bytes + 255) & ~(size_t)255;
        return p;
    };
    int* rank      = (int*)alloc((size_t)EE * 4);
    int* roundcnt  = (int*)alloc(64 * 4);          // [0..11] rounds, [32]=tm, [33]=necnt, [34]=ucnt, [35]=xcnt
    int* roundx    = (int*)alloc((size_t)MAXR * EE * 4);
    int* roundsrc  = (int*)alloc((size_t)MAXR * EE * 4);
    int* eidx      = (int*)alloc((size_t)EE * 4);
    int* xlist     = (int*)alloc((size_t)EE * 4);
    int* xsrc      = (int*)alloc((size_t)EE * 4);
    int* tx        = (int*)alloc((size_t)TSTEPS * (EE / 3 + 256) * 4);
    int* ulist     = (int*)alloc((size_t)NN * 4);
    int* nidx      = (int*)alloc((size_t)NN * 4);
    us* te_bf    = (us*)alloc((size_t)EE * 128 * 2);
    us* nf_bf    = (us*)alloc((size_t)NN * 256 * 2);
    us* ea_bf    = (us*)alloc((size_t)EE * 128 * 2);
    us* xh       = (us*)alloc((size_t)NN * 256 * 2);   // slist -> xpart_c -> hc
    float* memb  = (float*)alloc((size_t)NN * 256 * 4);
    us* memb_bf  = (us*)alloc((size_t)NN * 256 * 2);
    us* Wt_x    = (us*)alloc((size_t)256 * 512 * 2);
    us* Wt_a    = (us*)alloc((size_t)256 * 256 * 2);
    us* Wt_m2   = (us*)alloc((size_t)256 * 256 * 2);
    us* Wt_gate = (us*)alloc((size_t)1024 * 512 * 2);
    us* Wt_g    = (us*)alloc((size_t)256 * 512 * 2);
    us* Wt_e    = (us*)alloc((size_t)256 * 256 * 2);
    us* Wt_c    = (us*)alloc((size_t)128 * 256 * 2);
    us* Wk_a    = (us*)alloc((size_t)256 * 256 * 2);   // k-major bf16 (tail walker)
    us* Wk_m2   = (us*)alloc((size_t)256 * 256 * 2);
    us* Wk_ih   = (us*)alloc((size_t)256 * 768 * 2 * 2); // interleaved (Wi,Wh) pairs
    float* gvec  = (float*)alloc(256 * 4);
    float* sdot  = (float*)alloc((size_t)NN * 4);
    float* ddot  = (float*)alloc((size_t)NN * 4);
    float* edot  = (float*)alloc((size_t)EE * 4);
    float* logit = (float*)alloc((size_t)EE * 4);
    float* alpha = (float*)alloc((size_t)EE * 4);
    unsigned* mx = (unsigned*)alloc((size_t)NN * 4);
    float* denom = (float*)alloc((size_t)NN * 4);
    // zeroed mask zone (one memset): needed | uneed | scnt
    int* needed  = (int*)alloc((size_t)NN * 4);
    int* uneed   = (int*)alloc((size_t)NN * 4);
    int* scnt    = (int*)alloc((size_t)NN * 4);
    char* zone_end = base + off;

    size_t region = (ws_size > off + 4096) ? (ws_size - off - 4096) : 0;
    long capL = (long)(region / 3584);
    int CAPR = (int)(capL < 0 ? 0 : capL);
    CAPR = (CAPR / 128) * 128;
    if (CAPR > 28160) CAPR = 28160;
    if (CAPR < 1280) return;   // ws too small (visible failure)
    us* xbuf_bf  = (us*)alloc((size_t)CAPR * 256 * 2);
    us* msg_bf   = (us*)alloc((size_t)CAPR * 256 * 2);
    us* hprev_c  = (us*)alloc((size_t)CAPR * 256 * 2);
    us* gates_bf = (us*)alloc((size_t)CAPR * 1024 * 2);
    if (off > ws_size) return;

    unsigned* tm = (unsigned*)&roundcnt[32];
    int* necnt   = &roundcnt[33];
    int* ucnt    = &roundcnt[34];
    int* xcnt    = &roundcnt[35];
    // bucket-sort scratch aliases roundx (dead until k_chain)
    int* hist  = roundx;
    int* hcur  = roundx + NB;
    int* hbase = roundx + 2 * NB;
    int* blist = roundx + 3 * NB;
    // aliases in xh: slist (until k_chain) -> xpart_c (until tails) -> hc (after)
    int* slist = (int*)xh;
    us* xpart_c = xh;
    us* hc = xh;
    us* ef_c = nf_bf;                  // nf_bf dead after h-GEMM
    float* outb = memb;                // f32 mem dead post-scan
    us* pe_bf = te_bf;                 // te dead after ef GEMM
    float* c1 = (float*)(te_bf + (size_t)PP * 256);

    const dim3 B(256);
    const int gE = (EE + 255) / 256;
    const int gN = (NN + 255) / 256;

    hipMemsetAsync(roundcnt, 0, 64 * 4, stream);
    hipMemsetAsync(hist, 0, (size_t)2 * NB * 4, stream);                  // hist + hcur
    hipMemsetAsync(needed, 0, (size_t)(zone_end - (char*)needed), stream);
    hipMemsetAsync(Wt_gate, 0, (size_t)1024 * 512 * 2, stream);           // zero-pad for g2i/g2h halves

    // fused: needed-mask (first 16 blocks) + hist/slist/tmax prep
    k_prep<<<16 + gE, B, 0, stream>>>(pm, needed, t, src, hist, scnt, slist, tm);
    k_elist<<<gE, B, 0, stream>>>(src, dst, needed, necnt, eidx, uneed);
    k_ulist<<<gN, B, 0, stream>>>(uneed, ucnt, ulist, nidx);

    k_scanone<<<1, B, 0, stream>>>(hist, hbase);
    k_bscatter<<<gE, B, 0, stream>>>(t, hbase, hcur, blist);
    k_rank2<<<gE, B, 0, stream>>>(t, hbase, hist, blist, rank);
    k_chain<<<gE, B, 0, stream>>>(src, rank, scnt, slist, uneed, roundcnt, roundx, roundsrc,
                                  xcnt, xlist, xsrc);

    k_zcvt<<<1024, B, 0, stream>>>(ucnt, ulist, nf, nf_bf, memb, memb_bf);
    k_convL2<<<1024, B, 0, stream>>>(xcnt, xlist, necnt, eidx, t, wt, bt, te_bf, ea, ea_bf);

    // k-major bf16 weight copies + interleaved (Wi,Wh) pairs for the tail walker
    {
        int na4 = 256 * 256 / 4, nb4 = 256 * 256 / 4, nih = 256 * 768;
        int tot = na4 + nb4 + nih;
        k_wkflat<<<(tot + 255) / 256, B, 0, stream>>>(
            Wm1 + (size_t)256 * 256, Wk_a, na4, Wm2, Wk_m2, nb4, Wi, Wh, Wk_ih, nih);
    }

    // tiled weight transposes + gvec; Wt_gate = [Wi;Wh | g2i(Wi,0) | g2h(0,Wh)] (1024 x 512)
    {
        WtA wa;
        int o = 0;
        auto set = [&](int i, const float* W, us* dstp, int K, int N, int ld, int koff, int Ktot) {
            wa.d[i] = WtD{W, dstp, K, N, ld, koff, Ktot, o};
            o += (K >> 5) * (N >> 5);
        };
        set(0, Wm1, Wt_x, 256, 256, 256, 0, 512);
        set(1, Wm1 + (size_t)512 * 256, Wt_x, 128, 256, 256, 256, 512);
        set(2, Wm1 + (size_t)640 * 256, Wt_x, 128, 256, 256, 384, 512);
        set(3, Wm1 + (size_t)256 * 256, Wt_a, 256, 256, 256, 0, 256);
        set(4, Wm2, Wt_m2, 256, 256, 256, 0, 256);
        set(5, Wi, Wt_gate, 256, 512, 768, 0, 512);
        set(6, Wh, Wt_gate, 256, 512, 768, 256, 512);
        set(7, Wi + 512, Wt_gate + (size_t)512 * 512, 256, 256, 768, 0, 512);
        set(8, Wh + 512, Wt_gate + (size_t)768 * 512, 256, 256, 768, 256, 512);
        set(9, Wg, Wt_g, 512, 256, 256, 0, 512);
        set(10, We, Wt_e, 256, 256, 256, 0, 256);
        set(11, Wc1, Wt_c, 256, 128, 128, 0, 256);
        wa.ntiles = o;
        k_wt2<<<o + 1, B, 0, stream>>>(wa, tm, wt, bt, Wg, gvec);
    }

    // xpart (compact) = bm1 + nf[xsrc]@Wm1[0:256] + ea[xlist]@.. + te[xlist]@..
    const int gxE = (EE + 127) / 128;
    k_mgemm<<<dim3(gxE, 4), B, 0, stream>>>(nf_bf, 256, xsrc, ea_bf, 128, xlist,
        te_bf, 128, xlist, Wt_x, 512, 512, bm1, nullptr, nullptr,
        nullptr, xpart_c, 256, EE, xcnt, 0, 0, 0);

    // chain rounds 0..1: msg GEMM + fused gate GEMM + elementwise gate
    for (int j = 0; j < TANCH; ++j) {
        int bound = EE / 4;
        for (int cb = 0; cb < bound; cb += CAPR) {
            int m = bound - cb; if (m > CAPR) m = CAPR;
            int gx = (m + 127) / 128;
            const int* rx = roundx + (size_t)j * EE + cb;
            const int* rs = roundsrc + (size_t)j * EE + cb;
            if (j == 0) {
                k_mgemm<<<dim3(gx, 4), B, 0, stream>>>(xpart_c, 256, rx, nullptr, 0, nullptr,
                    nullptr, 0, nullptr, Wt_m2, 256, 256, bm2, nullptr, nullptr,
                    nullptr, msg_bf, 256, m, roundcnt + j, cb, 1, 1);
                k_mgemm<<<dim3(gx, 16), B, 0, stream>>>(msg_bf, 256, nullptr, nullptr, 0, nullptr,
                    nullptr, 0, nullptr, Wt_gate, 256, 512, nullptr, nullptr, nullptr,
                    nullptr, gates_bf, 1024, m, roundcnt + j, cb, 0, 0);
            } else {
                k_hgather<<<(m * 64 + 255) / 256, B, 0, stream>>>(roundcnt + j, cb, m, rs, memb_bf, hprev_c);
                k_mgemm<<<dim3(gx, 4), B, 0, stream>>>(hprev_c, 256, nullptr, nullptr, 0, nullptr,
                    nullptr, 0, nullptr, Wt_a, 256, 256, nullptr, xpart_c, rx,
                    nullptr, xbuf_bf, 256, m, roundcnt + j, cb, 1, 0);
                k_mgemm<<<dim3(gx, 4), B, 0, stream>>>(xbuf_bf, 256, nullptr, nullptr, 0, nullptr,
                    nullptr, 0, nullptr, Wt_m2, 256, 256, bm2, nullptr, nullptr,
                    nullptr, msg_bf, 256, m, roundcnt + j, cb, 1, 0);
                k_mgemm<<<dim3(gx, 16), B, 0, stream>>>(msg_bf, 256, nullptr, hprev_c, 256, nullptr,
                    nullptr, 0, nullptr, Wt_gate, 512, 512, nullptr, nullptr, nullptr,
                    nullptr, gates_bf, 1024, m, roundcnt + j, cb, 0, 0);
            }
            k_gate<<<2048, B, 0, stream>>>(roundcnt + j, cb, m, rs, gates_bf, bi, bh, memb, memb_bf);
        }
    }
    // tail rounds TANCH..11: fixed-grid chain walker (grid-stride over chains)
    k_tbuild<<<(EE / 3 + 255) / 256, B, 0, stream>>>(roundcnt, roundx, roundsrc, tx);
    k_tailchain<<<TGRID, dim3(1024), 0, stream>>>(roundcnt, roundsrc, tx, xpart_c,
                                                  Wk_a, Wk_m2, Wk_ih,
                                                  bm2, bi, bh, memb, memb_bf);

    k_zout<<<(PP * 64 + 255) / 256, B, 0, stream>>>(pm, outb, denom, mx);

    // h (compact U rows) = [nf | mem]@Wg + gvec bias
    const int gxN = (NN + 127) / 128;
    k_mgemm<<<dim3(gxN, 4), B, 0, stream>>>(nf_bf, 256, ulist, memb_bf, 256, ulist,
        nullptr, 0, nullptr, Wt_g, 512, 512, gvec, nullptr, nullptr,
        nullptr, hc, 256, NN, ucnt, 0, 0, 0);

    // ef (compact needed edges) = [ea | te](eidx) @ We
    k_mgemm<<<dim3(gxE, 4), B, 0, stream>>>(ea_bf, 128, eidx, te_bf, 128, eidx,
        nullptr, 0, nullptr, Wt_e, 256, 256, nullptr, nullptr, nullptr,
        nullptr, ef_c, 256, EE, necnt, 0, 0, 0);

    k_dots<<<2048, B, 0, stream>>>(hc, ef_c, ucnt, necnt, a_src, a_dst, a_e, sdot, ddot, edot);

    k_logitc<<<gE, B, 0, stream>>>(necnt, eidx, nidx, sdot, ddot, edot, src, dst, logit, mx);
    k_alphac<<<gE, B, 0, stream>>>(necnt, eidx, logit, dst, mx, alpha, denom);
    k_scatc<<<1024, B, 0, stream>>>(necnt, eidx, nidx, alpha, src, dst, hc, ef_c, outb);

    k_pe<<<PP, B, 0, stream>>>(pm, outb, denom, pe_bf);
    k_mgemm<<<dim3((PP + 127) / 128, 2), B, 0, stream>>>(pe_bf, 256, nullptr, nullptr, 0, nullptr,
        nullptr, 0, nullptr, Wt_c, 256, 256, bc1, nullptr, nullptr,
        c1, nullptr, 128, PP, nullptr, 0, 1, 0);
    k_final<<<(PP + 3) / 4, B, 0, stream>>>(c1, Wc2, bc2, outp);
}